// Round 6
// baseline (193.423 us; speedup 1.0000x reference)
//
#include <hip/hip_runtime.h>
#include <cstdint>
#include <cstddef>

typedef __attribute__((ext_vector_type(2))) _Float16 half2v;
typedef __attribute__((ext_vector_type(8))) _Float16 half8;
typedef __attribute__((ext_vector_type(4))) float floatx4;

typedef __attribute__((address_space(1))) const void gvoid_t;
typedef __attribute__((address_space(3))) void lvoid_t;

// ---------------------------------------------------------------------------
// Kernel 1: convert x (fp32 [M][K]) -> f16 [M][K] with within-8-chunk k-perm
// [0,4,1,5,2,6,3,7] so A fragments match the nibble-pair order the GEMM's
// register unpack of qweight produces (dot over k is order-invariant as long
// as A and B agree).
// ---------------------------------------------------------------------------
__global__ __launch_bounds__(256) void convert_x_kernel(
    const float* __restrict__ x, _Float16* __restrict__ xh, long long n)
{
    long long i = ((long long)blockIdx.x * 256 + threadIdx.x) * 8;
    if (i + 8 > n) return;
    const float4* p = (const float4*)(x + i);
    float4 a = p[0];   // k0..k3
    float4 b = p[1];   // k4..k7
    half8 h;
    h[0] = (_Float16)a.x; h[1] = (_Float16)b.x;   // k0,k4
    h[2] = (_Float16)a.y; h[3] = (_Float16)b.y;   // k1,k5
    h[4] = (_Float16)a.z; h[5] = (_Float16)b.z;   // k2,k6
    h[6] = (_Float16)a.w; h[7] = (_Float16)b.w;   // k3,k7
    *(half8*)(xh + i) = h;
}

// ---------------------------------------------------------------------------
// Fused GEMM: C = x_f16[M][K] * dequant(qweight)[K][N] + bias, fp32 out.
// R6: B never touches LDS. Each lane loads the single int32 qword holding
// its MFMA B-fragment's 8 nibbles and unpacks in registers via the f16
// magic trick: (q & 0x000F000F)|0x64006400 = f16 pair (1024+w_k, 1024+w_{k+4})
// EXACT; pk_sub exact (w-z); pk_mul by f16(s) (rel 2^-11, better than bf16).
// This halves LDS fragment traffic (the R5 co-bottleneck: 770 cyc LDS vs
// 620 cyc MFMA per block-tile) and deletes the dequant prologue + deqT
// entirely. A: R5 double-buffered glds staging (BK=64 swizzle, measured
// 0 conflicts). 2x16KB LDS. Groups of 128 k = 2 K-tiles share s/z; scale
// prefetch one group ahead.
// ---------------------------------------------------------------------------
#define BM 128
#define BN 128
#define BK 64

__device__ inline half8 unpack8(int q, half2v sh, half2v ch)
{
    unsigned uq = (unsigned)q;
    unsigned p0 = (uq & 0x000F000Fu) | 0x64006400u;
    unsigned p1 = ((uq >> 4) & 0x000F000Fu) | 0x64006400u;
    unsigned p2 = ((uq >> 8) & 0x000F000Fu) | 0x64006400u;
    unsigned p3 = ((uq >> 12) & 0x000F000Fu) | 0x64006400u;
    half2v v0 = (__builtin_bit_cast(half2v, p0) - ch) * sh;
    half2v v1 = (__builtin_bit_cast(half2v, p1) - ch) * sh;
    half2v v2 = (__builtin_bit_cast(half2v, p2) - ch) * sh;
    half2v v3 = (__builtin_bit_cast(half2v, p3) - ch) * sh;
    half8 r;
    r[0] = v0[0]; r[1] = v0[1]; r[2] = v1[0]; r[3] = v1[1];
    r[4] = v2[0]; r[5] = v2[1]; r[6] = v3[0]; r[7] = v3[1];
    return r;
}

__global__ __launch_bounds__(256) void gemm_fused(
    const _Float16* __restrict__ A, const int* __restrict__ qw,
    const float* __restrict__ scales, const float* __restrict__ zps,
    const float* __restrict__ bias, float* __restrict__ C,
    int M, int N, int K)
{
    __shared__ __align__(16) _Float16 a_lds[2][BM * BK];   // 2 x 16 KB

    const int t  = threadIdx.x;
    const int L  = t & 63;
    const int w  = t >> 6;
    const int m0 = blockIdx.y * BM;
    const int n0 = blockIdx.x * BN;
    const int wm = (w & 1) * 64;
    const int wn = (w >> 1) * 64;

    floatx4 acc[4][4] = {};

    // A staging: per inst i, wave w stages rows w*8 + 32*i + (L>>3);
    // chunk swizzle gc = sc ^ (row&7) (R1/R2/R5 pattern, measured 0 conflicts)
    const int sr = L >> 3;
    const int sc = L & 7;
    const int gc = sc ^ sr;
    const _Float16* ag = A + (size_t)(m0 + w * 8 + sr) * K + gc * 8;
    const int dst = (w * 8) * BK;

    // B/scale lane pointers: this lane's base column
    const int nc = n0 + wn + (L & 15);
    const int* qp = qw + (size_t)(L >> 4) * N + nc;
    const float* sp = scales + nc;
    const float* zp = zps + nc;

    const int NG = K / 128;        // groups; 2 K-tiles (BK=64) per group

    // ---- preload: A tile0 glds, B tile0 qwords, group-0 scales ----
    #pragma unroll
    for (int i = 0; i < 4; ++i)
        __builtin_amdgcn_global_load_lds(
            (gvoid_t*)(ag + (size_t)i * 32 * K),
            (lvoid_t*)(&a_lds[0][dst + i * 32 * BK]), 16, 0, 0);

    int qc[8], qm[8];
    #pragma unroll
    for (int s2 = 0; s2 < 2; ++s2)
        #pragma unroll
        for (int j = 0; j < 4; ++j)
            qc[s2 * 4 + j] = qp[(size_t)(s2 * 4) * N + 16 * j];

    half2v sh[4], ch[4];
    {
        #pragma unroll
        for (int j = 0; j < 4; ++j) {
            float s = fminf(fmaxf(sp[16 * j], 1e-5f), 1e4f);
            float z = fminf(fmaxf(rintf(zp[16 * j]), 0.0f), 15.0f);
            _Float16 hs = (_Float16)s;
            _Float16 hc = (_Float16)(1024.0f + z);
            sh[j][0] = hs; sh[j][1] = hs;
            ch[j][0] = hc; ch[j][1] = hc;
        }
    }

    auto compute = [&](int cur, const int* qarr) {
        #pragma unroll
        for (int s2 = 0; s2 < 2; ++s2) {
            const int p = (s2 * 4 + (L >> 4)) ^ (L & 7);   // swizzled LDS chunk
            half8 af[4];
            #pragma unroll
            for (int i = 0; i < 4; ++i)
                af[i] = *(const half8*)(&a_lds[cur][(wm + 16 * i + (L & 15)) * BK + p * 8]);
            #pragma unroll
            for (int j = 0; j < 4; ++j) {
                half8 bf = unpack8(qarr[s2 * 4 + j], sh[j], ch[j]);
                #pragma unroll
                for (int i = 0; i < 4; ++i)
                    acc[i][j] = __builtin_amdgcn_mfma_f32_16x16x32_f16(
                        af[i], bf, acc[i][j], 0, 0, 0);
            }
        }
    };

    for (int g = 0; g < NG; ++g) {
        const int t1 = 2 * g + 1;

        __syncthreads();    // A(2g) ready in buf 0 (drains loads issued last iter)

        // stage A(2g+1) into buf 1; prefetch B(2g+1) qwords
        #pragma unroll
        for (int i = 0; i < 4; ++i)
            __builtin_amdgcn_global_load_lds(
                (gvoid_t*)(ag + (size_t)i * 32 * K + (size_t)t1 * BK),
                (lvoid_t*)(&a_lds[1][dst + i * 32 * BK]), 16, 0, 0);
        #pragma unroll
        for (int s2 = 0; s2 < 2; ++s2)
            #pragma unroll
            for (int j = 0; j < 4; ++j)
                qm[s2 * 4 + j] = qp[(size_t)(t1 * 8 + s2 * 4) * N + 16 * j];

        compute(0, qc);

        __syncthreads();    // A(2g+1) ready (qm also drained — issued pre-compute)

        float snf[4], znf[4];
        if (g + 1 < NG) {
            const int t2 = 2 * g + 2;
            #pragma unroll
            for (int i = 0; i < 4; ++i)
                __builtin_amdgcn_global_load_lds(
                    (gvoid_t*)(ag + (size_t)i * 32 * K + (size_t)t2 * BK),
                    (lvoid_t*)(&a_lds[0][dst + i * 32 * BK]), 16, 0, 0);
            #pragma unroll
            for (int s2 = 0; s2 < 2; ++s2)
                #pragma unroll
                for (int j = 0; j < 4; ++j)
                    qc[s2 * 4 + j] = qp[(size_t)(t2 * 8 + s2 * 4) * N + 16 * j];
            #pragma unroll
            for (int j = 0; j < 4; ++j) {
                snf[j] = sp[(size_t)(g + 1) * N + 16 * j];
                znf[j] = zp[(size_t)(g + 1) * N + 16 * j];
            }
        }

        compute(1, qm);

        if (g + 1 < NG) {
            #pragma unroll
            for (int j = 0; j < 4; ++j) {
                float s = fminf(fmaxf(snf[j], 1e-5f), 1e4f);
                float z = fminf(fmaxf(rintf(znf[j]), 0.0f), 15.0f);
                _Float16 hs = (_Float16)s;
                _Float16 hc = (_Float16)(1024.0f + z);
                sh[j][0] = hs; sh[j][1] = hs;
                ch[j][0] = hc; ch[j][1] = hc;
            }
        }
    }

    // Epilogue: C/D layout col = lane&15, row = (lane>>4)*4 + reg  (m89/m91)
    float bv[4];
    #pragma unroll
    for (int j = 0; j < 4; ++j)
        bv[j] = bias[nc + 16 * j];
    const int col0 = nc;
    #pragma unroll
    for (int i = 0; i < 4; ++i) {
        const int row0 = m0 + wm + 16 * i + (L >> 4) * 4;
        #pragma unroll
        for (int r = 0; r < 4; ++r) {
            float* outr = C + (size_t)(row0 + r) * N + col0;
            #pragma unroll
            for (int j = 0; j < 4; ++j)
                outr[16 * j] = acc[i][j][r] + bv[j];
        }
    }
}

// ---------------------------------------------------------------------------
extern "C" void kernel_launch(void* const* d_in, const int* in_sizes, int n_in,
                              void* d_out, int out_size, void* d_ws, size_t ws_size,
                              hipStream_t stream)
{
    const float* x      = (const float*)d_in[0];
    const float* scales = (const float*)d_in[1];
    const float* zps    = (const float*)d_in[2];
    const float* bias   = (const float*)d_in[3];
    const int*   qw     = (const int*)d_in[4];

    const int N = in_sizes[3];          // outfeatures (bias length)
    const int G = in_sizes[1] / N;      // num groups
    const int K = G * 128;              // infeatures
    const int M = in_sizes[0] / K;      // tokens

    _Float16* xh = (_Float16*)d_ws;     // M*K f16 (k-permuted per 8-chunk)
    float* out   = (float*)d_out;

    const long long nx = (long long)M * K;
    convert_x_kernel<<<(int)(nx / 2048), 256, 0, stream>>>(x, xh, nx);
    gemm_fused<<<dim3(N / BN, M / BM), 256, 0, stream>>>(
        xh, qw, scales, zps, bias, out, M, N, K);
}

// Round 7
// 188.839 us; speedup vs baseline: 1.0243x; 1.0243x over previous
//
#include <hip/hip_runtime.h>
#include <cstdint>
#include <cstddef>

typedef __attribute__((ext_vector_type(2))) _Float16 half2v;
typedef __attribute__((ext_vector_type(8))) _Float16 half8;
typedef __attribute__((ext_vector_type(4))) float floatx4;

typedef __attribute__((address_space(1))) const void gvoid_t;
typedef __attribute__((address_space(3))) void lvoid_t;

// ---------------------------------------------------------------------------
// Kernel 1: convert x (fp32 [M][K]) -> f16 [M][K] with within-8-chunk k-perm
// [0,4,1,5,2,6,3,7], matching the nibble-pair order of the B unpack (dot
// over k is order-invariant when A and B agree; proven correct in R6).
// ---------------------------------------------------------------------------
__global__ __launch_bounds__(256) void convert_x_kernel(
    const float* __restrict__ x, _Float16* __restrict__ xh, long long n)
{
    long long i = ((long long)blockIdx.x * 256 + threadIdx.x) * 8;
    if (i + 8 > n) return;
    const float4* p = (const float4*)(x + i);
    float4 a = p[0];   // k0..k3
    float4 b = p[1];   // k4..k7
    half8 h;
    h[0] = (_Float16)a.x; h[1] = (_Float16)b.x;   // k0,k4
    h[2] = (_Float16)a.y; h[3] = (_Float16)b.y;   // k1,k5
    h[4] = (_Float16)a.z; h[5] = (_Float16)b.z;   // k2,k6
    h[6] = (_Float16)a.w; h[7] = (_Float16)b.w;   // k3,k7
    *(half8*)(xh + i) = h;
}

// f16 magic unpack: one int32 -> 8 dequantized f16 in pair order (j, j+4).
// (1024+w) exact in f16; pk_sub exact (w-z); pk_mul by f16(s).
__device__ inline half8 unpack8(int q, half2v sh, half2v ch)
{
    unsigned uq = (unsigned)q;
    unsigned p0 = (uq & 0x000F000Fu) | 0x64006400u;
    unsigned p1 = ((uq >> 4) & 0x000F000Fu) | 0x64006400u;
    unsigned p2 = ((uq >> 8) & 0x000F000Fu) | 0x64006400u;
    unsigned p3 = ((uq >> 12) & 0x000F000Fu) | 0x64006400u;
    half2v v0 = (__builtin_bit_cast(half2v, p0) - ch) * sh;
    half2v v1 = (__builtin_bit_cast(half2v, p1) - ch) * sh;
    half2v v2 = (__builtin_bit_cast(half2v, p2) - ch) * sh;
    half2v v3 = (__builtin_bit_cast(half2v, p3) - ch) * sh;
    half8 r;
    r[0] = v0[0]; r[1] = v0[1]; r[2] = v1[0]; r[3] = v1[1];
    r[4] = v2[0]; r[5] = v2[1]; r[6] = v3[0]; r[7] = v3[1];
    return r;
}

// ---------------------------------------------------------------------------
// Kernel 2: dequantize qweight into MFMA B-FRAGMENT layout:
//   Bf[(n16)*(K/32) + k32][lane L][8 halves], 1KB per fragment.
// Fragment (n16, k32): lane L holds col n16*16+(L&15), k-subchunk (L>>4),
// i.e. exactly one qword qw[4*k32 + (L>>4)][col] -> unpack8 -> 16B store.
// Reads: 4x64B fully-consumed segments per load inst; writes: 1KB/wave
// contiguous. Unpack VALU amortized ONCE (R6's mistake: per M-block).
// Grid: (N/16) x (K/32/16); each block's 4 waves do 16 frags.
// ---------------------------------------------------------------------------
__global__ __launch_bounds__(256) void dequant_frag_kernel(
    const int* __restrict__ qw, const float* __restrict__ scales,
    const float* __restrict__ zps, _Float16* __restrict__ Bf,
    int N, int K)
{
    const int t = threadIdx.x, L = t & 63, w = t >> 6;
    const int n16 = blockIdx.x;
    const int n = n16 * 16 + (L & 15);
    const int KF = K / 32;
    const int f0 = blockIdx.y * 16;

    #pragma unroll
    for (int i = 0; i < 4; ++i) {
        const int f = f0 + i * 4 + w;          // frag k-index (k32 block)
        const int r = f * 4 + (L >> 4);        // qw row
        const int q = qw[(size_t)r * N + n];
        const int g = f >> 2;                  // quant group (128 k / 4 frags)

        float s = fminf(fmaxf(scales[(size_t)g * N + n], 1e-5f), 1e4f);
        float z = fminf(fmaxf(rintf(zps[(size_t)g * N + n]), 0.0f), 15.0f);
        _Float16 hs = (_Float16)s;
        _Float16 hc = (_Float16)(1024.0f + z);
        half2v sh; sh[0] = hs; sh[1] = hs;
        half2v ch; ch[0] = hc; ch[1] = hc;

        half8 h = unpack8(q, sh, ch);
        *(half8*)(Bf + ((size_t)n16 * KF + f) * 512 + (size_t)L * 8) = h;
    }
}

// ---------------------------------------------------------------------------
// Kernel 3: GEMM. A f16 from LDS (double-buffered glds, BK=64 swizzle,
// measured 0 conflicts); B f16 fragments loaded global->VGPR (16B/lane =
// 1KB/wave coalesced), register double-buffered one K-tile ahead. LDS pipe
// now carries A only (~20us busy < 33us MFMA floor). Grid: m-tiles on x
// (fastest) so consecutive blocks share the same B strip -> L2/L3 reuse.
// ---------------------------------------------------------------------------
#define BM 128
#define BN 128
#define BK 64

__global__ __launch_bounds__(256) void gemm_bfrag(
    const _Float16* __restrict__ A, const _Float16* __restrict__ Bf,
    const float* __restrict__ bias, float* __restrict__ C,
    int M, int N, int K)
{
    __shared__ __align__(16) _Float16 a_lds[2][BM * BK];   // 2 x 16 KB

    const int t  = threadIdx.x;
    const int L  = t & 63;
    const int w  = t >> 6;
    const int m0 = blockIdx.x * BM;       // m fastest
    const int n0 = blockIdx.y * BN;
    const int wm = (w & 1) * 64;
    const int wn = (w >> 1) * 64;

    floatx4 acc[4][4] = {};

    // A staging (R5 pattern, 0 conflicts): wave w stages rows w*8+32i+(L>>3),
    // global chunk (L&7)^(L>>3) at LDS pos (L&7).
    const int sr = L >> 3;
    const int sc = L & 7;
    const int gc = sc ^ sr;
    const _Float16* ag = A + (size_t)(m0 + w * 8 + sr) * K + gc * 8;
    const int dst = (w * 8) * BK;

    // B fragment lane pointers, one per column-group j
    const int KF = K / 32;
    const _Float16* bp[4];
    #pragma unroll
    for (int j = 0; j < 4; ++j)
        bp[j] = Bf + ((size_t)(n0 / 16 + (w >> 1) * 4 + j) * KF) * 512
                   + (size_t)L * 8;

    const int NK = K / BK;                // 64 (even)
    half8 b0[8], b1[8];

    // ---- preload tile 0 ----
    #pragma unroll
    for (int i = 0; i < 4; ++i)
        __builtin_amdgcn_global_load_lds(
            (gvoid_t*)(ag + (size_t)i * 32 * K),
            (lvoid_t*)(&a_lds[0][dst + i * 32 * BK]), 16, 0, 0);
    #pragma unroll
    for (int j = 0; j < 4; ++j) {
        b0[j * 2 + 0] = *(const half8*)(bp[j] + 0);
        b0[j * 2 + 1] = *(const half8*)(bp[j] + 512);
    }

    auto compute = [&](int cur, const half8* barr) {
        #pragma unroll
        for (int s2 = 0; s2 < 2; ++s2) {
            const int p = (s2 * 4 + (L >> 4)) ^ (L & 7);   // swizzled LDS chunk
            half8 af[4];
            #pragma unroll
            for (int i = 0; i < 4; ++i)
                af[i] = *(const half8*)(&a_lds[cur][(wm + 16 * i + (L & 15)) * BK + p * 8]);
            #pragma unroll
            for (int j = 0; j < 4; ++j) {
                #pragma unroll
                for (int i = 0; i < 4; ++i)
                    acc[i][j] = __builtin_amdgcn_mfma_f32_16x16x32_f16(
                        af[i], barr[j * 2 + s2], acc[i][j], 0, 0, 0);
            }
        }
    };

    for (int ti = 0; ti < NK; ti += 2) {
        __syncthreads();                       // A(ti) ready in buf 0
        {   // prefetch tile ti+1 (always exists: NK even, ti+1 <= NK-1)
            const size_t kn = (size_t)(ti + 1) * BK;
            #pragma unroll
            for (int i = 0; i < 4; ++i)
                __builtin_amdgcn_global_load_lds(
                    (gvoid_t*)(ag + (size_t)i * 32 * K + kn),
                    (lvoid_t*)(&a_lds[1][dst + i * 32 * BK]), 16, 0, 0);
            #pragma unroll
            for (int j = 0; j < 4; ++j) {
                b1[j * 2 + 0] = *(const half8*)(bp[j] + (size_t)(ti + 1) * 1024);
                b1[j * 2 + 1] = *(const half8*)(bp[j] + (size_t)(ti + 1) * 1024 + 512);
            }
        }
        compute(0, b0);

        __syncthreads();                       // A(ti+1) ready in buf 1
        if (ti + 2 < NK) {
            const size_t kn = (size_t)(ti + 2) * BK;
            #pragma unroll
            for (int i = 0; i < 4; ++i)
                __builtin_amdgcn_global_load_lds(
                    (gvoid_t*)(ag + (size_t)i * 32 * K + kn),
                    (lvoid_t*)(&a_lds[0][dst + i * 32 * BK]), 16, 0, 0);
            #pragma unroll
            for (int j = 0; j < 4; ++j) {
                b0[j * 2 + 0] = *(const half8*)(bp[j] + (size_t)(ti + 2) * 1024);
                b0[j * 2 + 1] = *(const half8*)(bp[j] + (size_t)(ti + 2) * 1024 + 512);
            }
        }
        compute(1, b1);
    }

    // Epilogue: C/D layout col = lane&15, row = (lane>>4)*4 + reg  (m89/m91)
    const int nc = n0 + wn + (L & 15);
    float bv[4];
    #pragma unroll
    for (int j = 0; j < 4; ++j)
        bv[j] = bias[nc + 16 * j];
    #pragma unroll
    for (int i = 0; i < 4; ++i) {
        const int row0 = m0 + wm + 16 * i + (L >> 4) * 4;
        #pragma unroll
        for (int r = 0; r < 4; ++r) {
            float* outr = C + (size_t)(row0 + r) * N + nc;
            #pragma unroll
            for (int j = 0; j < 4; ++j)
                outr[16 * j] = acc[i][j][r] + bv[j];
        }
    }
}

// ---------------------------------------------------------------------------
extern "C" void kernel_launch(void* const* d_in, const int* in_sizes, int n_in,
                              void* d_out, int out_size, void* d_ws, size_t ws_size,
                              hipStream_t stream)
{
    const float* x      = (const float*)d_in[0];
    const float* scales = (const float*)d_in[1];
    const float* zps    = (const float*)d_in[2];
    const float* bias   = (const float*)d_in[3];
    const int*   qw     = (const int*)d_in[4];

    const int N = in_sizes[3];          // outfeatures (bias length)
    const int G = in_sizes[1] / N;      // num groups
    const int K = G * 128;              // infeatures
    const int M = in_sizes[0] / K;      // tokens

    _Float16* xh = (_Float16*)d_ws;                 // M*K f16 (k-perm per 8)
    _Float16* Bf = xh + (size_t)M * K;              // N/16 * K/32 frags, 1KB each
    float* out   = (float*)d_out;

    const long long nx = (long long)M * K;
    convert_x_kernel<<<(int)(nx / 2048), 256, 0, stream>>>(x, xh, nx);
    dequant_frag_kernel<<<dim3(N / 16, K / 512), 256, 0, stream>>>(
        qw, scales, zps, Bf, N, K);
    gemm_bfrag<<<dim3(M / BM, N / BN), 256, 0, stream>>>(
        xh, Bf, bias, out, M, N, K);
}

// Round 8
// 166.676 us; speedup vs baseline: 1.1605x; 1.1330x over previous
//
#include <hip/hip_runtime.h>
#include <cstdint>
#include <cstddef>

typedef __attribute__((ext_vector_type(8))) short short8;
typedef __attribute__((ext_vector_type(4))) float floatx4;

typedef __attribute__((address_space(1))) const void gvoid_t;
typedef __attribute__((address_space(3))) void lvoid_t;

// fp32 -> bf16 with round-to-nearest-even (bit pattern as short)
__device__ inline short f2bf(float f) {
    unsigned u = __float_as_uint(f);
    u = (u + 0x7FFFu + ((u >> 16) & 1u)) >> 16;
    return (short)u;
}

// ---------------------------------------------------------------------------
// Merged prologue: blocks [0,ncvt) convert x fp32->bf16; blocks [ncvt,..)
// dequantize qweight into transposed bf16 deqT [N][K]. Both memory-bound,
// measured jointly ~15us ~= 88MB/6.3TBps roofline.
// ---------------------------------------------------------------------------
__global__ __launch_bounds__(256) void prologue_kernel(
    const float* __restrict__ x, short* __restrict__ xb, long long nx, int ncvt,
    const int* __restrict__ qw, const float* __restrict__ scales,
    const float* __restrict__ zps, short* __restrict__ deqT,
    int N, int K, int nbx)
{
    __shared__ int lds_q[32 * 65];
    const int t = threadIdx.x;

    if ((int)blockIdx.x < ncvt) {
        // ---- convert x ----
        long long i = ((long long)blockIdx.x * 256 + t) * 8;
        if (i + 8 > nx) return;
        const float4* p = (const float4*)(x + i);
        float4 v0 = p[0];
        float4 v1 = p[1];
        short8 h;
        h[0] = f2bf(v0.x); h[1] = f2bf(v0.y); h[2] = f2bf(v0.z); h[3] = f2bf(v0.w);
        h[4] = f2bf(v1.x); h[5] = f2bf(v1.y); h[6] = f2bf(v1.z); h[7] = f2bf(v1.w);
        *(short8*)(xb + i) = h;
        return;
    }

    // ---- dequant ----
    const int b2 = (int)blockIdx.x - ncvt;
    const int n0 = (b2 % nbx) * 64;
    const int r0 = (b2 / nbx) * 32;   // qweight row tile (32 rows = 256 k)

    // Phase 1: coalesced load of the 32x64 int32 tile into LDS (pad 65)
    #pragma unroll
    for (int v = 0; v < 2; ++v) {
        int idx = t + v * 256;            // 0..511 int4-chunks
        int row = idx >> 4;               // 16 int4 per 64-col row
        int c4  = (idx & 15) * 4;
        const int4 q4 = *(const int4*)(qw + (size_t)(r0 + row) * N + n0 + c4);
        int base = row * 65 + c4;
        lds_q[base + 0] = q4.x;
        lds_q[base + 1] = q4.y;
        lds_q[base + 2] = q4.z;
        lds_q[base + 3] = q4.w;
    }
    __syncthreads();

    const int L  = t & 63;
    const int w  = t >> 6;
    const int rq = L & 31;            // qw row this lane unpacks
    const int hi = L >> 5;            // 0: row 2p, 1: row 2p+1
    const int g  = (r0 + rq) >> 4;    // quant group of this lane's 8 k-values

    #pragma unroll
    for (int it = 0; it < 8; ++it) {
        const int p  = w * 8 + it;    // row-pair index 0..31
        const int nl = 2 * p + hi;    // local n row 0..63

        float s = scales[(size_t)g * N + n0 + nl];
        s = fminf(fmaxf(s, 1e-5f), 1e4f);
        float z = rintf(zps[(size_t)g * N + n0 + nl]);
        z = fminf(fmaxf(z, 0.0f), 15.0f);

        const int q = lds_q[rq * 65 + nl];
        short8 h;
        #pragma unroll
        for (int j = 0; j < 8; ++j) {
            float f = (float)((q >> (4 * j)) & 15);
            h[j] = f2bf((f - z) * s);
        }
        // lanes 0-31: 512B contiguous (row 2p), lanes 32-63: row 2p+1
        *(short8*)(deqT + (size_t)(n0 + nl) * K + (size_t)(r0 + rq) * 8) = h;
    }
}

// ---------------------------------------------------------------------------
// Kernel 2: bf16 GEMM, C = A[M][K] * Bt[N][K]^T + bias, fp32 out.
// R5 structure (best measured: 77.4us, 888 TF, 0 bank conflicts):
// single-barrier double-buffered K-loop, BK=64, 2x(16+16)KB LDS.
// R8 adds XCD-aware block swizzle: flat id -> XCD k = id%8 owns n-strips
// [4k,4k+4) x all m-tiles, so each XCD's L2 holds a 4MB B working set and
// A tiles get x4 in-XCD reuse (default order gave every XCD all 16 A strips
// + 4 scattered B strips = 20MB through 4MB L2; GEMM FETCH 82MB vs 48 ideal).
// Mapping is performance-only (G16-safe).
// ---------------------------------------------------------------------------
#define BM 128
#define BN 128
#define BK 64

__global__ __launch_bounds__(256) void gemm_bf16_bt(
    const short* __restrict__ A, const short* __restrict__ Bt,
    const float* __restrict__ bias, float* __restrict__ C,
    int M, int N, int K)
{
    __shared__ __align__(16) short a_lds[2][BM * BK];   // 2 x 16 KB
    __shared__ __align__(16) short b_lds[2][BN * BK];   // 2 x 16 KB

    const int t  = threadIdx.x;
    const int L  = t & 63;
    const int w  = t >> 6;

    // XCD swizzle: id%8 = XCD (dispatch round-robins consecutive ids across
    // XCDs). XCD k gets n-tiles 4k..4k+3 for every m-tile.
    const int nbn = N / BN;                    // n-tiles (32)
    const int id  = blockIdx.y * gridDim.x + blockIdx.x;
    const int xcd = id & 7;
    const int loc = id >> 3;                   // 0..63 per XCD
    const int gsz = nbn / 8;                   // n-tiles per XCD group (4)
    const int nt  = xcd * gsz + (loc % gsz);
    const int mt  = loc / gsz;
    const int m0  = mt * BM;
    const int n0  = nt * BN;

    const int wm = (w & 1) * 64;
    const int wn = (w >> 1) * 64;

    floatx4 acc[4][4] = {};

    // staging: per inst i, wave w covers rows w*8 + 32*i + (L>>3);
    // LDS slot = uniform base + lane*16B (hardware-enforced order).
    const int sr = L >> 3;            // row within the wave's 8-row window
    const int sc = L & 7;             // 16B-chunk position within row (0..7)
    const int gc = sc ^ sr;           // global chunk staged at LDS pos sc
    const short* ag = A  + (size_t)(m0 + w * 8 + sr) * K + gc * 8;
    const short* bg = Bt + (size_t)(n0 + w * 8 + sr) * K + gc * 8;
    const int dst = (w * 8) * BK;     // wave-uniform offset within buffer

    const int NK = K / BK;

    // prologue: stage tile 0 into buffer 0
    #pragma unroll
    for (int i = 0; i < 4; ++i) {
        __builtin_amdgcn_global_load_lds(
            (gvoid_t*)(ag + (size_t)i * 32 * K),
            (lvoid_t*)(&a_lds[0][dst + i * 32 * BK]), 16, 0, 0);
        __builtin_amdgcn_global_load_lds(
            (gvoid_t*)(bg + (size_t)i * 32 * K),
            (lvoid_t*)(&b_lds[0][dst + i * 32 * BK]), 16, 0, 0);
    }

    for (int ti = 0; ti < NK; ++ti) {
        const int cur = ti & 1;
        // drains cur's loads (in flight for a full compute phase, except ti=0)
        // + guarantees all waves finished reading buf cur^1
        __syncthreads();

        if (ti + 1 < NK) {
            const int kn = (ti + 1) * BK;
            #pragma unroll
            for (int i = 0; i < 4; ++i) {
                __builtin_amdgcn_global_load_lds(
                    (gvoid_t*)(ag + (size_t)i * 32 * K + kn),
                    (lvoid_t*)(&a_lds[cur ^ 1][dst + i * 32 * BK]), 16, 0, 0);
                __builtin_amdgcn_global_load_lds(
                    (gvoid_t*)(bg + (size_t)i * 32 * K + kn),
                    (lvoid_t*)(&b_lds[cur ^ 1][dst + i * 32 * BK]), 16, 0, 0);
            }
        }

        #pragma unroll
        for (int s = 0; s < 2; ++s) {
            // global chunk c = s*4 + (L>>4) of row r (r&7 == L&7):
            const int p = (s * 4 + (L >> 4)) ^ (L & 7);  // swizzled LDS pos
            short8 af[4], bfr[4];
            #pragma unroll
            for (int i = 0; i < 4; ++i)
                af[i] = *(const short8*)(&a_lds[cur][(wm + 16 * i + (L & 15)) * BK + p * 8]);
            #pragma unroll
            for (int j = 0; j < 4; ++j)
                bfr[j] = *(const short8*)(&b_lds[cur][(wn + 16 * j + (L & 15)) * BK + p * 8]);
            #pragma unroll
            for (int i = 0; i < 4; ++i) {
                #pragma unroll
                for (int j = 0; j < 4; ++j)
                    acc[i][j] = __builtin_amdgcn_mfma_f32_16x16x32_bf16(
                        af[i], bfr[j], acc[i][j], 0, 0, 0);
            }
        }
    }

    // Epilogue: C/D layout col = lane&15, row = (lane>>4)*4 + reg  (m89/m91)
    float bv[4];
    #pragma unroll
    for (int j = 0; j < 4; ++j)
        bv[j] = bias[n0 + wn + 16 * j + (L & 15)];
    const int col0 = n0 + wn + (L & 15);
    #pragma unroll
    for (int i = 0; i < 4; ++i) {
        const int row0 = m0 + wm + 16 * i + (L >> 4) * 4;
        #pragma unroll
        for (int r = 0; r < 4; ++r) {
            float* outr = C + (size_t)(row0 + r) * N + col0;
            #pragma unroll
            for (int j = 0; j < 4; ++j)
                outr[16 * j] = acc[i][j][r] + bv[j];
        }
    }
}

// ---------------------------------------------------------------------------
extern "C" void kernel_launch(void* const* d_in, const int* in_sizes, int n_in,
                              void* d_out, int out_size, void* d_ws, size_t ws_size,
                              hipStream_t stream)
{
    const float* x      = (const float*)d_in[0];
    const float* scales = (const float*)d_in[1];
    const float* zps    = (const float*)d_in[2];
    const float* bias   = (const float*)d_in[3];
    const int*   qw     = (const int*)d_in[4];

    const int N = in_sizes[3];          // outfeatures (bias length)
    const int G = in_sizes[1] / N;      // num groups
    const int K = G * 128;              // infeatures
    const int M = in_sizes[0] / K;      // tokens

    short* xb   = (short*)d_ws;                       // M*K bf16
    short* deqT = xb + (size_t)M * K;                 // N*K bf16
    float* out  = (float*)d_out;

    const long long nx = (long long)M * K;
    const int ncvt = (int)(nx / 2048);
    const int nbx  = N / 64;
    const int ndq  = nbx * (K / 256);

    prologue_kernel<<<ncvt + ndq, 256, 0, stream>>>(
        x, xb, nx, ncvt, qw, scales, zps, deqT, N, K, nbx);
    gemm_bf16_bt<<<dim3(N / BN, M / BM), 256, 0, stream>>>(xb, deqT, bias, out, M, N, K);
}